// Round 2
// baseline (156.810 us; speedup 1.0000x reference)
//
#include <hip/hip_runtime.h>

#define KEPS 1e-16f
#define RS 102  // LDS row stride in floats: rows 8B-aligned (408B), banks 6r%32 -> 4-way max

__device__ __forceinline__ float fast_sigmoid(float v) {
    // 1 / (1 + exp(-v)); v_exp + v_rcp, ~1ulp each — far within 0.0156 absmax.
    return __builtin_amdgcn_rcpf(1.0f + __expf(-v));
}

__global__ __launch_bounds__(128) void kitsune_fused(
    const float* __restrict__ x,           // [B][100]
    const float* __restrict__ tail_enc_w,  // [10][8][10]
    const float* __restrict__ tail_enc_b,  // [10][8]
    const float* __restrict__ tail_dec_w,  // [10][10][8]
    const float* __restrict__ tail_dec_b,  // [10][10]
    const float* __restrict__ tail_nmin,   // [10][10]
    const float* __restrict__ tail_nmax,   // [10][10]
    const float* __restrict__ head_enc_w,  // [8][10]
    const float* __restrict__ head_enc_b,  // [8]
    const float* __restrict__ head_dec_w,  // [10][8]
    const float* __restrict__ head_dec_b,  // [10]
    const float* __restrict__ head_nmin,   // [10]
    const float* __restrict__ head_nmax,   // [10]
    float* __restrict__ out_xhat,          // [B][10]
    float* __restrict__ out_t,             // [B][10]
    int B)
{
    __shared__ float lds[2 * 64 * RS];

    const int l = threadIdx.x & 63;        // lane = row within wave tile
    const int w = threadIdx.x >> 6;        // wave id in block
    float* slice = lds + w * (64 * RS);

    const int blockRow0 = blockIdx.x * 128;
    if (blockRow0 >= B) return;                       // block-uniform exit
    const int tileRow0 = blockRow0 + w * 64;          // this wave's first row
    int rh = B - tileRow0;                            // rows in this wave's tile
    rh = rh < 0 ? 0 : (rh > 64 ? 64 : rh);

    // ---- stage 64 rows x 100 floats, fully coalesced float4 loads ----
    // global float4 index == linear tile index (row*25 + q), so loads are contiguous.
    {
        const float4* gsrc = reinterpret_cast<const float4*>(x + (size_t)tileRow0 * 100);
        #pragma unroll
        for (int i = 0; i < 25; ++i) {
            unsigned idx = i * 64 + l;            // [0,1600)
            unsigned row = idx / 25u;             // magic-mul div
            unsigned q   = idx - row * 25u;       // float4 slot within row
            if ((int)row < rh) {
                float4 v = gsrc[idx];
                float* dst = slice + row * RS + q * 4;
                *reinterpret_cast<float2*>(dst)     = make_float2(v.x, v.y);
                *reinterpret_cast<float2*>(dst + 2) = make_float2(v.z, v.w);
            }
        }
    }
    __syncthreads();

    // ---- per-row compute (lane l owns row l of its wave tile) ----
    if (l < rh) {
        const float* xr = slice + l * RS;
        float tails[10];

        for (int c = 0; c < 10; ++c) {   // not unrolled: wave-uniform weight idx -> s_loads
            float xn[10];
            #pragma unroll
            for (int j = 0; j < 5; ++j) {
                float2 v = *reinterpret_cast<const float2*>(xr + c * 10 + 2 * j);
                xn[2 * j]     = v.x;
                xn[2 * j + 1] = v.y;
            }
            #pragma unroll
            for (int f = 0; f < 10; ++f) {
                float nmin = tail_nmin[c * 10 + f];
                float r = __builtin_amdgcn_rcpf(tail_nmax[c * 10 + f] - nmin + KEPS);
                xn[f] = (xn[f] - nmin) * r;
            }

            float h[8];
            #pragma unroll
            for (int i = 0; i < 8; ++i) {
                float acc = tail_enc_b[c * 8 + i];
                #pragma unroll
                for (int f = 0; f < 10; ++f)
                    acc = fmaf(tail_enc_w[(c * 8 + i) * 10 + f], xn[f], acc);
                h[i] = fast_sigmoid(acc);
            }

            float ss = 0.0f;
            #pragma unroll
            for (int f = 0; f < 10; ++f) {
                float acc = tail_dec_b[c * 10 + f];
                #pragma unroll
                for (int i = 0; i < 8; ++i)
                    acc = fmaf(tail_dec_w[(c * 10 + f) * 8 + i], h[i], acc);
                float rec = fast_sigmoid(acc);
                float d = rec - xn[f];
                ss = fmaf(d, d, ss);
            }
            float loss = __fsqrt_rn(ss * 0.1f);
            tails[c] = (loss == 0.0f) ? 0.01f : loss;
        }

        // head
        float t[10];
        #pragma unroll
        for (int c = 0; c < 10; ++c) {
            float nmin = head_nmin[c];
            float r = __builtin_amdgcn_rcpf(head_nmax[c] - nmin + KEPS);
            t[c] = (tails[c] - nmin) * r;
        }
        float hh[8];
        #pragma unroll
        for (int i = 0; i < 8; ++i) {
            float acc = head_enc_b[i];
            #pragma unroll
            for (int c = 0; c < 10; ++c)
                acc = fmaf(head_enc_w[i * 10 + c], t[c], acc);
            hh[i] = fast_sigmoid(acc);
        }
        float xh[10];
        #pragma unroll
        for (int c = 0; c < 10; ++c) {
            float acc = head_dec_b[c];
            #pragma unroll
            for (int i = 0; i < 8; ++i)
                acc = fmaf(head_dec_w[c * 8 + i], hh[i], acc);
            xh[c] = fast_sigmoid(acc);
        }

        // stash outputs in own row of LDS (cols 0..9 = xhat, 10..19 = t)
        float* orow = slice + l * RS;
        #pragma unroll
        for (int j = 0; j < 5; ++j) {
            *reinterpret_cast<float2*>(orow + 2 * j)      = make_float2(xh[2 * j], xh[2 * j + 1]);
            *reinterpret_cast<float2*>(orow + 10 + 2 * j) = make_float2(t[2 * j],  t[2 * j + 1]);
        }
    }
    __syncthreads();

    // ---- coalesced stores: 64 rows x 10 floats per output ----
    {
        float* gx = out_xhat + (size_t)tileRow0 * 10;
        float* gt = out_t    + (size_t)tileRow0 * 10;
        #pragma unroll
        for (int i = 0; i < 5; ++i) {
            unsigned idx = i * 64 + l;            // [0,320) float2 slots
            unsigned row = idx / 5u;
            unsigned c2  = idx - row * 5u;        // float2 within row
            if ((int)row < rh) {
                float2 a = *reinterpret_cast<const float2*>(slice + row * RS + c2 * 2);
                float2 b = *reinterpret_cast<const float2*>(slice + row * RS + 10 + c2 * 2);
                *reinterpret_cast<float2*>(gx + row * 10 + c2 * 2) = a;
                *reinterpret_cast<float2*>(gt + row * 10 + c2 * 2) = b;
            }
        }
    }
}

extern "C" void kernel_launch(void* const* d_in, const int* in_sizes, int n_in,
                              void* d_out, int out_size, void* d_ws, size_t ws_size,
                              hipStream_t stream) {
    const float* x          = (const float*)d_in[0];
    const float* tail_enc_w = (const float*)d_in[1];
    const float* tail_enc_b = (const float*)d_in[2];
    const float* tail_dec_w = (const float*)d_in[3];
    const float* tail_dec_b = (const float*)d_in[4];
    const float* tail_nmin  = (const float*)d_in[5];
    const float* tail_nmax  = (const float*)d_in[6];
    const float* head_enc_w = (const float*)d_in[7];
    const float* head_enc_b = (const float*)d_in[8];
    const float* head_dec_w = (const float*)d_in[9];
    const float* head_dec_b = (const float*)d_in[10];
    const float* head_nmin  = (const float*)d_in[11];
    const float* head_nmax  = (const float*)d_in[12];

    const int B = in_sizes[0] / 100;

    float* out_xhat = (float*)d_out;             // [B][10], first in tuple
    float* out_t    = out_xhat + (size_t)B * 10; // [B][10], second in tuple

    const int block = 128;                        // 2 waves; LDS 52KB -> 3 blocks/CU
    const int grid  = (B + block - 1) / block;
    kitsune_fused<<<grid, block, 0, stream>>>(
        x, tail_enc_w, tail_enc_b, tail_dec_w, tail_dec_b,
        tail_nmin, tail_nmax, head_enc_w, head_enc_b,
        head_dec_w, head_dec_b, head_nmin, head_nmax,
        out_xhat, out_t, B);
}

// Round 3
// 98.129 us; speedup vs baseline: 1.5980x; 1.5980x over previous
//
#include <hip/hip_runtime.h>

#define KEPS 1e-16f

__device__ __forceinline__ float fast_sigmoid(float v) {
    // 1 / (1 + exp(-v)); v_exp + v_rcp, ~1ulp each — far within 0.0156 absmax.
    return __builtin_amdgcn_rcpf(1.0f + __expf(-v));
}

__global__ __launch_bounds__(256, 3) void kitsune_fused(
    const float* __restrict__ x,           // [B][100]
    const float* __restrict__ tail_enc_w,  // [10][8][10]
    const float* __restrict__ tail_enc_b,  // [10][8]
    const float* __restrict__ tail_dec_w,  // [10][10][8]
    const float* __restrict__ tail_dec_b,  // [10][10]
    const float* __restrict__ tail_nmin,   // [10][10]
    const float* __restrict__ tail_nmax,   // [10][10]
    const float* __restrict__ head_enc_w,  // [8][10]
    const float* __restrict__ head_enc_b,  // [8]
    const float* __restrict__ head_dec_w,  // [10][8]
    const float* __restrict__ head_dec_b,  // [10]
    const float* __restrict__ head_nmin,   // [10]
    const float* __restrict__ head_nmax,   // [10]
    float* __restrict__ out_xhat,          // [B][10]
    float* __restrict__ out_t,             // [B][10]
    int B)
{
    const int b = blockIdx.x * blockDim.x + threadIdx.x;
    if (b >= B) return;

    // ---- one tight burst: whole 400B row -> 25 float4 loads -> registers.
    // All indices compile-time so xr[] lives in VGPRs (no scratch).
    // Lines are fully consumed while resident -> no L2-eviction re-fetch.
    float xr[100];
    {
        const float4* g = reinterpret_cast<const float4*>(x + (size_t)b * 100);
        #pragma unroll
        for (int q = 0; q < 25; ++q) {
            float4 v = g[q];
            xr[4 * q + 0] = v.x;
            xr[4 * q + 1] = v.y;
            xr[4 * q + 2] = v.z;
            xr[4 * q + 3] = v.w;
        }
    }

    float tails[10];

    // Fully unrolled: c is compile-time -> xr[] indices constant (registers),
    // weight indices wave-uniform with immediate offsets -> scalar loads.
    #pragma unroll
    for (int c = 0; c < 10; ++c) {
        float xn[10];
        #pragma unroll
        for (int f = 0; f < 10; ++f) {
            float nmin = tail_nmin[c * 10 + f];
            float r = __builtin_amdgcn_rcpf(tail_nmax[c * 10 + f] - nmin + KEPS);
            xn[f] = (xr[c * 10 + f] - nmin) * r;
        }

        float h[8];
        #pragma unroll
        for (int i = 0; i < 8; ++i) {
            float acc = tail_enc_b[c * 8 + i];
            #pragma unroll
            for (int f = 0; f < 10; ++f)
                acc = fmaf(tail_enc_w[(c * 8 + i) * 10 + f], xn[f], acc);
            h[i] = fast_sigmoid(acc);
        }

        float ss = 0.0f;
        #pragma unroll
        for (int f = 0; f < 10; ++f) {
            float acc = tail_dec_b[c * 10 + f];
            #pragma unroll
            for (int i = 0; i < 8; ++i)
                acc = fmaf(tail_dec_w[(c * 10 + f) * 8 + i], h[i], acc);
            float rec = fast_sigmoid(acc);
            float d = rec - xn[f];
            ss = fmaf(d, d, ss);
        }
        float loss = __fsqrt_rn(ss * 0.1f);
        tails[c] = (loss == 0.0f) ? 0.01f : loss;
    }

    // ---- head ----
    float t[10];
    #pragma unroll
    for (int c = 0; c < 10; ++c) {
        float nmin = head_nmin[c];
        float r = __builtin_amdgcn_rcpf(head_nmax[c] - nmin + KEPS);
        t[c] = (tails[c] - nmin) * r;
    }

    float hh[8];
    #pragma unroll
    for (int i = 0; i < 8; ++i) {
        float acc = head_enc_b[i];
        #pragma unroll
        for (int c = 0; c < 10; ++c)
            acc = fmaf(head_enc_w[i * 10 + c], t[c], acc);
        hh[i] = fast_sigmoid(acc);
    }

    float xh[10];
    #pragma unroll
    for (int c = 0; c < 10; ++c) {
        float acc = head_dec_b[c];
        #pragma unroll
        for (int i = 0; i < 8; ++i)
            acc = fmaf(head_dec_w[c * 8 + i], hh[i], acc);
        xh[c] = fast_sigmoid(acc);
    }

    // ---- stores: rows are 40B -> only 8B-aligned for odd b, so float2 ----
    float* po = out_xhat + (size_t)b * 10;
    float* pt = out_t    + (size_t)b * 10;
    #pragma unroll
    for (int j = 0; j < 5; ++j) {
        *reinterpret_cast<float2*>(po + 2 * j) = make_float2(xh[2 * j], xh[2 * j + 1]);
        *reinterpret_cast<float2*>(pt + 2 * j) = make_float2(t[2 * j], t[2 * j + 1]);
    }
}

extern "C" void kernel_launch(void* const* d_in, const int* in_sizes, int n_in,
                              void* d_out, int out_size, void* d_ws, size_t ws_size,
                              hipStream_t stream) {
    const float* x          = (const float*)d_in[0];
    const float* tail_enc_w = (const float*)d_in[1];
    const float* tail_enc_b = (const float*)d_in[2];
    const float* tail_dec_w = (const float*)d_in[3];
    const float* tail_dec_b = (const float*)d_in[4];
    const float* tail_nmin  = (const float*)d_in[5];
    const float* tail_nmax  = (const float*)d_in[6];
    const float* head_enc_w = (const float*)d_in[7];
    const float* head_enc_b = (const float*)d_in[8];
    const float* head_dec_w = (const float*)d_in[9];
    const float* head_dec_b = (const float*)d_in[10];
    const float* head_nmin  = (const float*)d_in[11];
    const float* head_nmax  = (const float*)d_in[12];

    const int B = in_sizes[0] / 100;

    float* out_xhat = (float*)d_out;             // [B][10], first in tuple
    float* out_t    = out_xhat + (size_t)B * 10; // [B][10], second in tuple

    const int block = 256;
    const int grid  = (B + block - 1) / block;
    kitsune_fused<<<grid, block, 0, stream>>>(
        x, tail_enc_w, tail_enc_b, tail_dec_w, tail_dec_b,
        tail_nmin, tail_nmax, head_enc_w, head_enc_b,
        head_dec_w, head_dec_b, head_nmin, head_nmax,
        out_xhat, out_t, B);
}